// Round 12
// baseline (156.518 us; speedup 1.0000x reference)
//
#include <hip/hip_runtime.h>

// ---------------------------------------------------------------------------
// Sparse3DNA: x->QKV proj (bf16 MFMA GEMM), 3x3x3 causal window attention
// (+BOS), output proj. Shapes: b=2, T=4096 (4x32x32), DIM=512, 8 heads x 64.
// R12: attn v5 — patch-LDS. One block per (b, f, 8x8 patch, head); stage the
// 201 halo K/V rows to LDS once (coalesced), 64 queries read scattered slots
// at LDS latency. Kills the 16-segment-per-instruction K gather that made v4
// 4x its VALU floor. GEMMs = R9 dbuf gemm_nt (best of 6 variants).
// Budget (R10 measurement): F~75us harness-fixed; attn 28, gemm1 14, gemm2 6,
// cast 5, gaps 7.
// ---------------------------------------------------------------------------

#define T_TOK   4096
#define DIM     512
#define NQKV    1536

typedef unsigned short u16;
typedef unsigned int   u32;
typedef unsigned long long u64;
typedef __attribute__((ext_vector_type(8))) short short8;   // 8 bf16 (4 VGPR)
typedef __attribute__((ext_vector_type(4))) float f32x4;

__device__ __forceinline__ u16 f2bf(float f) {           // RNE float->bf16
    u32 u = __float_as_uint(f);
    return (u16)((u + 0x7fffu + ((u >> 16) & 1u)) >> 16);
}
__device__ __forceinline__ float b2f(u16 u) {
    return __uint_as_float(((u32)u) << 16);
}

__device__ __forceinline__ void gload_lds16(const void* g, void* l) {
    // async global->LDS, 16B/lane; LDS dest = wave-uniform base + lane*16
    __builtin_amdgcn_global_load_lds(
        (const __attribute__((address_space(1))) void*)g,
        (__attribute__((address_space(3))) void*)l, 16, 0, 0);
}

// ---------------------------------------------------------------------------
// merged cast kernel.
//  blocks [0,4096): x fp32 -> bf16 (vectorized)
//  blocks [4096,4288): Wt[n][k] = [Wq|Wk|Wv](k,n), LDS-tiled 64x64 transpose
//  blocks [4288,4352): Wot[n][k] = Wo[k][n], same
// ---------------------------------------------------------------------------
__global__ void cast_all_kernel(const float4* __restrict__ x,
                                const float* __restrict__ Wq, const float* __restrict__ Wkv,
                                const float* __restrict__ Wo,
                                u16* __restrict__ xb, u16* __restrict__ Wt,
                                u16* __restrict__ Wot) {
    __shared__ float S[64 * 65];
    int blk = blockIdx.x;
    int tid = threadIdx.x;
    if (blk < 4096) {
        int i = blk * 256 + tid;                  // 1,048,576 float4s
        float4 v = x[i];
        u64 pack = (u64)f2bf(v.x) | ((u64)f2bf(v.y) << 16) |
                   ((u64)f2bf(v.z) << 32) | ((u64)f2bf(v.w) << 48);
        ((u64*)xb)[i] = pack;
        return;
    }
    int isWo = blk >= 4288;
    int tIdx = isWo ? (blk - 4288) : (blk - 4096);
    int tn = tIdx >> 3, tk = tIdx & 7;            // n-tile, k-tile
    #pragma unroll
    for (int p = 0; p < 16; ++p) {                // stage, coalesced over n
        int kl = p * 4 + (tid >> 6), nl = tid & 63;
        int gk = tk * 64 + kl, gn = tn * 64 + nl;
        float v;
        if (isWo)            v = Wo[gk * 512 + gn];
        else if (gn < 512)   v = Wq[gk * 512 + gn];
        else                 v = Wkv[gk * 1024 + (gn - 512)];
        S[kl * 65 + nl] = v;
    }
    __syncthreads();
    u16* dst = isWo ? Wot : Wt;
    #pragma unroll
    for (int p = 0; p < 16; ++p) {                // write, coalesced over k
        int nl = p * 4 + (tid >> 6), kl = tid & 63;
        dst[(size_t)(tn * 64 + nl) * 512 + tk * 64 + kl] = f2bf(S[kl * 65 + nl]);
    }
}

// ---------------------------------------------------------------------------
// NT GEMM, double-buffered (R6/R9 best-of-6): C = A * B^T, K=512, bf16.
// BMxBN / block, 4 waves (2x2), mfma 16x16x32, BK=32, XOR-swizzled LDS.
// K-loop: stage(ks+1 -> buf^1); s_waitcnt vmcnt(NLD); s_barrier; frags+MFMA;
// lgkmcnt(0); s_barrier.  MODE 0: bf16 store. MODE 1: fp32 store + bias.
// ---------------------------------------------------------------------------
template <int BM, int BN, int MODE>
__global__ __launch_bounds__(256)
void gemm_nt(const u16* __restrict__ A, const u16* __restrict__ B,
             void* __restrict__ Cv, const float* __restrict__ bias,
             int lda, int ldb, int ldc) {
    constexpr int K = 512, BK = 32, KSTEPS = K / BK;
    constexpr int ACH = BM * 4;                  // A 16B-chunks per K-step
    constexpr int NCH = (BM + BN) * 4;
    constexpr int NLD = NCH / 256;               // chunks per thread per stage
    constexpr int ABYTES = BM * 64;
    constexpr int HALF = (BM + BN) * 64;         // one buffer
    constexpr int MI = BM / 32, NJ = BN / 32;
    __shared__ __align__(16) char lds[2 * HALF];
    const int tid  = threadIdx.x;
    const int lane = tid & 63, wave = tid >> 6;
    const int quad = lane >> 4, mrow = lane & 15;
    const int wm = wave >> 1, wn = wave & 1;
    const int bm = blockIdx.y, bn = blockIdx.x;

    const char* gptr[NLD];
    char*       lptr[NLD];
    #pragma unroll
    for (int it = 0; it < NLD; ++it) {
        int c   = it * 256 + tid;                // chunk id, lane-consecutive
        int inB = (c >= ACH);
        int a   = inB ? c - ACH : c;
        int r   = a >> 2;                        // tile row
        int kc  = ((a & 3) - (r >> 1)) & 3;      // inverse swizzle
        int row = (inB ? bn * BN : bm * BM) + r;
        const u16* base = inB ? B : A;
        int ld = inB ? ldb : lda;
        gptr[it] = (const char*)(base + (size_t)row * ld + kc * 8);
        lptr[it] = (char*)lds + (it * 256 + wave * 64) * 16;   // wave-uniform
    }
    const char* aLds[MI];
    const char* bLds[NJ];
    #pragma unroll
    for (int i = 0; i < MI; ++i) {
        int ra = wm * (BM / 2) + i * 16 + mrow;
        aLds[i] = lds + (ra * 4 + ((quad + (ra >> 1)) & 3)) * 16;
    }
    #pragma unroll
    for (int j = 0; j < NJ; ++j) {
        int rb = wn * (BN / 2) + j * 16 + mrow;
        bLds[j] = lds + ABYTES + (rb * 4 + ((quad + (rb >> 1)) & 3)) * 16;
    }

    f32x4 acc[MI][NJ] = {};
    #pragma unroll
    for (int it = 0; it < NLD; ++it)             // prologue: stage 0 -> buf 0
        gload_lds16(gptr[it], lptr[it]);

    #pragma unroll
    for (int ks = 0; ks < KSTEPS; ++ks) {
        const int cur = ks & 1;
        if (ks + 1 < KSTEPS) {                   // prefetch next stage
            #pragma unroll
            for (int it = 0; it < NLD; ++it)
                gload_lds16(gptr[it] + 2 * (ks + 1) * BK, lptr[it] + (cur ^ 1) * HALF);
            asm volatile("s_waitcnt vmcnt(%0)" :: "i"(NLD) : "memory");
        } else {
            asm volatile("s_waitcnt vmcnt(0)" ::: "memory");
        }
        asm volatile("s_barrier" ::: "memory");  // stage ks visible to all

        short8 af[MI], bf[NJ];
        #pragma unroll
        for (int i = 0; i < MI; ++i) af[i] = *(const short8*)(aLds[i] + cur * HALF);
        #pragma unroll
        for (int j = 0; j < NJ; ++j) bf[j] = *(const short8*)(bLds[j] + cur * HALF);
        #pragma unroll
        for (int i = 0; i < MI; ++i)
            #pragma unroll
            for (int j = 0; j < NJ; ++j)
                acc[i][j] = __builtin_amdgcn_mfma_f32_16x16x32_bf16(af[i], bf[j], acc[i][j], 0, 0, 0);
        asm volatile("s_waitcnt lgkmcnt(0)" ::: "memory");
        asm volatile("s_barrier" ::: "memory");  // all waves done reading buf
    }

    // epilogue: D row = quad*4 + reg, col = lane&15 (m89-verified layout)
    #pragma unroll
    for (int i = 0; i < MI; ++i) {
        #pragma unroll
        for (int j = 0; j < NJ; ++j) {
            int colg = bn * BN + wn * (BN / 2) + j * 16 + mrow;
            #pragma unroll
            for (int r = 0; r < 4; ++r) {
                int rowg = bm * BM + wm * (BM / 2) + i * 16 + quad * 4 + r;
                if (MODE == 0) {
                    ((u16*)Cv)[(size_t)rowg * ldc + colg] = f2bf(acc[i][j][r]);
                } else {
                    ((float*)Cv)[(size_t)rowg * ldc + colg] = acc[i][j][r] + bias[colg];
                }
            }
        }
    }
}

// ---------------------------------------------------------------------------
// Attention v5 (patch-LDS): one block (256 thr) per (b, f, 8x8 patch, head).
// Grid 1024.  LDS: K/V for the 2x10x10 halo (200 rows) + BOS (row 200),
// 64 bf16 each.  K rows chunk-swizzled: 16B chunk c -> pos (c + 2*row)&7
// (keeps ds_read_b128 <=4-way on banks); V plain (lane=dim 2B reads, 2-way
// free).  Staging fully coalesced (256B runs), one __syncthreads.
// Queries: 16 per wave, serial; lane=(j,g) for scores, lane=dim for PV.
// Local row r = (df+1)*100 + (dh+hq-ph+1)*10 + (dw+wq-pw+1); masked -> 200.
// ---------------------------------------------------------------------------
__global__ __launch_bounds__(256)
void attn_patch(const u16* __restrict__ QKV, u16* __restrict__ O) {
    __shared__ u16 Ksh[201 * 64];
    __shared__ u16 Vsh[201 * 64];
    const int blk = blockIdx.x;
    const int b = blk >> 9, rem = blk & 511;
    const int f = rem >> 7, pid = (rem >> 3) & 15, h = rem & 7;
    const int ph = (pid >> 2) * 8, pw = (pid & 3) * 8;
    const size_t baseQ = (size_t)b * T_TOK * NQKV;
    const size_t baseO = (size_t)b * T_TOK * DIM;
    const int tid = threadIdx.x;

    // ---- stage 201 rows x {K,V} as 16B chunks: c = row*16 + kv*8 + part
    for (int c = tid; c < 201 * 16; c += 256) {
        int row = c >> 4, pp = c & 15;
        int kv = pp >> 3, part = pp & 7;
        int p = 0, val = 1;
        if (row < 200) {
            int plane = row / 100, rr = row % 100;
            int hz = ph - 1 + rr / 10, wz = pw - 1 + rr % 10;
            int fz = f - 1 + plane;
            val = (fz >= 0) && ((unsigned)hz < 32u) && ((unsigned)wz < 32u);
            p = ((fz << 10) + (hz << 5) + wz) + 1;
        }
        int dpart = kv ? part : ((part + 2 * row) & 7);
        u16* dst = (kv ? Vsh : Ksh) + row * 64 + dpart * 8;
        if (val) {
            const u16* src = QKV + baseQ + (size_t)p * NQKV +
                             (kv ? 1024 : 512) + h * 64 + part * 8;
            *(short8*)dst = *(const short8*)src;
        } else {
            short8 z = {};
            *(short8*)dst = z;
        }
    }
    __syncthreads();

    if (f == 0 && pid == 0 && tid < 64)          // output row 0 = bos_v
        O[baseO + h * 64 + tid] = Vsh[200 * 64 + tid];

    const int wave = tid >> 6, lane = tid & 63;
    const int j = lane >> 2, g = lane & 3;
    // slot decode (query-independent)
    int jm1 = j - 1;
    int dh9 = ((jm1 * 11) >> 5) - 1;             // j in 1..9: (j-1)/3 - 1
    int dw9 = jm1 - (dh9 + 1) * 3 - 1;           // j in 1..9: (j-1)%3 - 1
    int df = (j >= 1 && j <= 9) ? -1 : 0;
    int dh = (j >= 1 && j <= 9) ? dh9 : ((j >= 10 && j <= 12) ? -1 : 0);
    int dw = (j >= 1 && j <= 9) ? dw9 :
             ((j >= 10 && j <= 12) ? (j - 11) : ((j == 13) ? -1 : 0));
    const int jok = (j >= 1) && (j <= 14) && (f + df >= 0);

    for (int s = 0; s < 16; ++s) {
        int qi = wave * 16 + s;
        int hq = ph + (qi >> 3), wq = pw + (qi & 7);
        int t = (f << 10) + (hq << 5) + wq;
        if (t == 4095) continue;                 // wave-uniform; no output row
        int nh = hq + dh, nw = wq + dw;
        int valid = jok && ((unsigned)nh < 32u) && ((unsigned)nw < 32u);
        int r = (j == 0) ? 200
              : (valid ? ((df + 1) * 100 + (dh + hq - ph + 1) * 10 +
                          (dw + wq - pw + 1)) : 200);
        int score_on = valid || (j == 0);

        // Q from global (row broadcast across j-lanes)
        const u16* qrow = QKV + baseQ + (size_t)(t + 1) * NQKV + h * 64 + g * 16;
        short8 q0 = *(const short8*)qrow;
        short8 q1 = *(const short8*)(qrow + 8);
        // K from LDS (swizzled chunks)
        int c0 = (2 * g + 2 * r) & 7;            // even; c0+1 adjacent
        const u16* kp = Ksh + r * 64 + c0 * 8;
        short8 k0 = *(const short8*)kp;
        short8 k1 = *(const short8*)(kp + 8);

        float sdot = 0.f;
        #pragma unroll
        for (int i = 0; i < 8; ++i) {
            sdot = fmaf(b2f((u16)q0[i]), b2f((u16)k0[i]), sdot);
            sdot = fmaf(b2f((u16)q1[i]), b2f((u16)k1[i]), sdot);
        }
        sdot += __shfl_xor(sdot, 1);
        sdot += __shfl_xor(sdot, 2);             // 4 g-lanes of slot j -> dot_j
        sdot *= 0.125f;                          // SCALE
        sdot = score_on ? sdot : -3.0e38f;

        float m = sdot;
        #pragma unroll
        for (int off = 4; off <= 32; off <<= 1) m = fmaxf(m, __shfl_xor(m, off));
        float pe = __expf(sdot - m);             // masked lanes -> 0
        float l = pe;
        #pragma unroll
        for (int off = 4; off <= 32; off <<= 1) l += __shfl_xor(l, off);
        float pen = pe * __frcp_rn(l);           // normalized, wave-wide

        // PV from LDS, lane = dim
        float acc = 0.f;
        #pragma unroll
        for (int jj = 0; jj < 15; ++jj) {
            int   rr2 = __builtin_amdgcn_readlane(r, jj * 4);
            float pj  = __uint_as_float(
                          (u32)__builtin_amdgcn_readlane((int)__float_as_uint(pen), jj * 4));
            acc = fmaf(pj, b2f(Vsh[rr2 * 64 + lane]), acc);
        }
        O[baseO + (size_t)(t + 1) * DIM + h * 64 + lane] = f2bf(acc);
    }
}

// ---------------------------------------------------------------------------
// launch: cast -> gemm1 (QKV) -> attn -> gemm2 (out proj + bias)
// ws layout (bytes): xb 8M @0 | Wt 1.5M @8388608 | Wot 0.5M @9961472 |
//                    QKV 24M @10485760 | O aliases xb @0   (total ~34MB)
// ---------------------------------------------------------------------------
extern "C" void kernel_launch(void* const* d_in, const int* in_sizes, int n_in,
                              void* d_out, int out_size, void* d_ws, size_t ws_size,
                              hipStream_t stream) {
    const float* x   = (const float*)d_in[0];
    const float* Wq  = (const float*)d_in[1];
    const float* Wkv = (const float*)d_in[2];
    const float* Wo  = (const float*)d_in[3];
    const float* bo  = (const float*)d_in[4];
    float* out = (float*)d_out;
    char* ws = (char*)d_ws;

    u16* xb  = (u16*)(ws + 0);
    u16* Wt  = (u16*)(ws + 8388608);
    u16* Wot = (u16*)(ws + 9961472);
    u16* QKV = (u16*)(ws + 10485760);
    u16* O   = (u16*)(ws + 0);          // aliases xb (dead after gemm1)

    cast_all_kernel<<<dim3(4352), dim3(256), 0, stream>>>(
        (const float4*)x, Wq, Wkv, Wo, xb, Wt, Wot);
    gemm_nt<128, 128, 0><<<dim3(12, 64), dim3(256), 0, stream>>>(
        xb, Wt, (void*)QKV, nullptr, 512, 512, 1536);
    attn_patch<<<dim3(1024), dim3(256), 0, stream>>>(QKV, O);
    gemm_nt<128, 64, 1><<<dim3(8, 64), dim3(256), 0, stream>>>(
        O, Wot, (void*)out, bo, 512, 512, 512);
}

// Round 13
// 134.299 us; speedup vs baseline: 1.1654x; 1.1654x over previous
//
#include <hip/hip_runtime.h>

// ---------------------------------------------------------------------------
// Sparse3DNA: x->QKV proj (bf16 MFMA GEMM), 3x3x3 causal window attention
// (+BOS), output proj. Shapes: b=2, T=4096 (4x32x32), DIM=512, 8 heads x 64.
// R13: attn v6 — FOUR heads per wave (v4 structure, doubled ILP again).
// Slot decode shared; 4 independent K/dot/softmax/V chains interleave.
// Wave count 16384. GEMMs/cast = R9 (best: 134.8us).
// Budget (R10): F~75us harness-fixed; attn 28, gemm1 14, gemm2 6, cast 5.
// ---------------------------------------------------------------------------

#define T_TOK   4096
#define DIM     512
#define NQKV    1536

typedef unsigned short u16;
typedef unsigned int   u32;
typedef unsigned long long u64;
typedef __attribute__((ext_vector_type(8))) short short8;   // 8 bf16 (4 VGPR)
typedef __attribute__((ext_vector_type(4))) float f32x4;

__device__ __forceinline__ u16 f2bf(float f) {           // RNE float->bf16
    u32 u = __float_as_uint(f);
    return (u16)((u + 0x7fffu + ((u >> 16) & 1u)) >> 16);
}
__device__ __forceinline__ float b2f(u16 u) {
    return __uint_as_float(((u32)u) << 16);
}

__device__ __forceinline__ void gload_lds16(const void* g, void* l) {
    // async global->LDS, 16B/lane; LDS dest = wave-uniform base + lane*16
    __builtin_amdgcn_global_load_lds(
        (const __attribute__((address_space(1))) void*)g,
        (__attribute__((address_space(3))) void*)l, 16, 0, 0);
}

// ---------------------------------------------------------------------------
// merged cast kernel.
//  blocks [0,4096): x fp32 -> bf16 (vectorized)
//  blocks [4096,4288): Wt[n][k] = [Wq|Wk|Wv](k,n), LDS-tiled 64x64 transpose
//  blocks [4288,4352): Wot[n][k] = Wo[k][n], same
// ---------------------------------------------------------------------------
__global__ void cast_all_kernel(const float4* __restrict__ x,
                                const float* __restrict__ Wq, const float* __restrict__ Wkv,
                                const float* __restrict__ Wo,
                                u16* __restrict__ xb, u16* __restrict__ Wt,
                                u16* __restrict__ Wot) {
    __shared__ float S[64 * 65];
    int blk = blockIdx.x;
    int tid = threadIdx.x;
    if (blk < 4096) {
        int i = blk * 256 + tid;                  // 1,048,576 float4s
        float4 v = x[i];
        u64 pack = (u64)f2bf(v.x) | ((u64)f2bf(v.y) << 16) |
                   ((u64)f2bf(v.z) << 32) | ((u64)f2bf(v.w) << 48);
        ((u64*)xb)[i] = pack;
        return;
    }
    int isWo = blk >= 4288;
    int tIdx = isWo ? (blk - 4288) : (blk - 4096);
    int tn = tIdx >> 3, tk = tIdx & 7;            // n-tile, k-tile
    #pragma unroll
    for (int p = 0; p < 16; ++p) {                // stage, coalesced over n
        int kl = p * 4 + (tid >> 6), nl = tid & 63;
        int gk = tk * 64 + kl, gn = tn * 64 + nl;
        float v;
        if (isWo)            v = Wo[gk * 512 + gn];
        else if (gn < 512)   v = Wq[gk * 512 + gn];
        else                 v = Wkv[gk * 1024 + (gn - 512)];
        S[kl * 65 + nl] = v;
    }
    __syncthreads();
    u16* dst = isWo ? Wot : Wt;
    #pragma unroll
    for (int p = 0; p < 16; ++p) {                // write, coalesced over k
        int nl = p * 4 + (tid >> 6), kl = tid & 63;
        dst[(size_t)(tn * 64 + nl) * 512 + tk * 64 + kl] = f2bf(S[kl * 65 + nl]);
    }
}

// ---------------------------------------------------------------------------
// NT GEMM, double-buffered (best of 6 variants): C = A * B^T, K=512, bf16.
// BMxBN / block, 4 waves (2x2), mfma 16x16x32, BK=32, XOR-swizzled LDS.
// K-loop: stage(ks+1 -> buf^1); s_waitcnt vmcnt(NLD); s_barrier; frags+MFMA;
// lgkmcnt(0); s_barrier.  MODE 0: bf16 store. MODE 1: fp32 store + bias.
// ---------------------------------------------------------------------------
template <int BM, int BN, int MODE>
__global__ __launch_bounds__(256)
void gemm_nt(const u16* __restrict__ A, const u16* __restrict__ B,
             void* __restrict__ Cv, const float* __restrict__ bias,
             int lda, int ldb, int ldc) {
    constexpr int K = 512, BK = 32, KSTEPS = K / BK;
    constexpr int ACH = BM * 4;                  // A 16B-chunks per K-step
    constexpr int NCH = (BM + BN) * 4;
    constexpr int NLD = NCH / 256;               // chunks per thread per stage
    constexpr int ABYTES = BM * 64;
    constexpr int HALF = (BM + BN) * 64;         // one buffer
    constexpr int MI = BM / 32, NJ = BN / 32;
    __shared__ __align__(16) char lds[2 * HALF];
    const int tid  = threadIdx.x;
    const int lane = tid & 63, wave = tid >> 6;
    const int quad = lane >> 4, mrow = lane & 15;
    const int wm = wave >> 1, wn = wave & 1;
    const int bm = blockIdx.y, bn = blockIdx.x;

    const char* gptr[NLD];
    char*       lptr[NLD];
    #pragma unroll
    for (int it = 0; it < NLD; ++it) {
        int c   = it * 256 + tid;                // chunk id, lane-consecutive
        int inB = (c >= ACH);
        int a   = inB ? c - ACH : c;
        int r   = a >> 2;                        // tile row
        int kc  = ((a & 3) - (r >> 1)) & 3;      // inverse swizzle
        int row = (inB ? bn * BN : bm * BM) + r;
        const u16* base = inB ? B : A;
        int ld = inB ? ldb : lda;
        gptr[it] = (const char*)(base + (size_t)row * ld + kc * 8);
        lptr[it] = (char*)lds + (it * 256 + wave * 64) * 16;   // wave-uniform
    }
    const char* aLds[MI];
    const char* bLds[NJ];
    #pragma unroll
    for (int i = 0; i < MI; ++i) {
        int ra = wm * (BM / 2) + i * 16 + mrow;
        aLds[i] = lds + (ra * 4 + ((quad + (ra >> 1)) & 3)) * 16;
    }
    #pragma unroll
    for (int j = 0; j < NJ; ++j) {
        int rb = wn * (BN / 2) + j * 16 + mrow;
        bLds[j] = lds + ABYTES + (rb * 4 + ((quad + (rb >> 1)) & 3)) * 16;
    }

    f32x4 acc[MI][NJ] = {};
    #pragma unroll
    for (int it = 0; it < NLD; ++it)             // prologue: stage 0 -> buf 0
        gload_lds16(gptr[it], lptr[it]);

    #pragma unroll
    for (int ks = 0; ks < KSTEPS; ++ks) {
        const int cur = ks & 1;
        if (ks + 1 < KSTEPS) {                   // prefetch next stage
            #pragma unroll
            for (int it = 0; it < NLD; ++it)
                gload_lds16(gptr[it] + 2 * (ks + 1) * BK, lptr[it] + (cur ^ 1) * HALF);
            asm volatile("s_waitcnt vmcnt(%0)" :: "i"(NLD) : "memory");
        } else {
            asm volatile("s_waitcnt vmcnt(0)" ::: "memory");
        }
        asm volatile("s_barrier" ::: "memory");  // stage ks visible to all

        short8 af[MI], bf[NJ];
        #pragma unroll
        for (int i = 0; i < MI; ++i) af[i] = *(const short8*)(aLds[i] + cur * HALF);
        #pragma unroll
        for (int j = 0; j < NJ; ++j) bf[j] = *(const short8*)(bLds[j] + cur * HALF);
        #pragma unroll
        for (int i = 0; i < MI; ++i)
            #pragma unroll
            for (int j = 0; j < NJ; ++j)
                acc[i][j] = __builtin_amdgcn_mfma_f32_16x16x32_bf16(af[i], bf[j], acc[i][j], 0, 0, 0);
        asm volatile("s_waitcnt lgkmcnt(0)" ::: "memory");
        asm volatile("s_barrier" ::: "memory");  // all waves done reading buf
    }

    // epilogue: D row = quad*4 + reg, col = lane&15 (m89-verified layout)
    #pragma unroll
    for (int i = 0; i < MI; ++i) {
        #pragma unroll
        for (int j = 0; j < NJ; ++j) {
            int colg = bn * BN + wn * (BN / 2) + j * 16 + mrow;
            #pragma unroll
            for (int r = 0; r < 4; ++r) {
                int rowg = bm * BM + wm * (BM / 2) + i * 16 + quad * 4 + r;
                if (MODE == 0) {
                    ((u16*)Cv)[(size_t)rowg * ldc + colg] = f2bf(acc[i][j][r]);
                } else {
                    ((float*)Cv)[(size_t)rowg * ldc + colg] = acc[i][j][r] + bias[colg];
                }
            }
        }
    }
}

// ---------------------------------------------------------------------------
// Attention v6: one wave per (b, head-QUAD, ti) — 16384 waves.
// Slot decode (p, valid, voff) head-independent: computed once per wave.
// Four heads (hp*4 .. hp*4+3) run as independent interleaved chains:
//   phase 1: 4x (Q,K loads; dot; 2-shfl reduce); batched softmax per head
//            (4-shfl max, 1 exp, 4-shfl sum, rcp-normalize) — interleaved.
//   phase 2: shared readlane(voff); 4x (V load + readlane pj + fma).
// 4x memory-level parallelism per wave for the latency-bound kernel.
// ---------------------------------------------------------------------------
__global__ __launch_bounds__(256)
void attn_kernel(const u16* __restrict__ QKV, u16* __restrict__ O) {
    const int wid  = blockIdx.x * 4 + (threadIdx.x >> 6);   // 0..16383
    const int lane = threadIdx.x & 63;
    const int b  = wid >> 13;             // 2
    const int hp = (wid >> 12) & 1;       // head quad (0..1)
    const int ti = wid & 4095;            // 4096
    const size_t baseQ = (size_t)b * T_TOK * NQKV;
    const size_t baseO = (size_t)b * T_TOK * DIM;
    const int hbase = hp * 256;           // byte-col of head quad start (u16s)

    if (ti == 0) {                        // output row 0 = bos_v (4 heads)
        #pragma unroll
        for (int hd = 0; hd < 4; ++hd)
            O[baseO + hbase + hd * 64 + lane] =
                QKV[baseQ + 1024 + hbase + hd * 64 + lane];
        return;
    }
    const int t = ti - 1;                 // grid position, 0..4094
    const int f = t >> 10, hh = (t >> 5) & 31, ww = t & 31;

    // ---- per-lane slot decode (wave-uniform t; j varies per lane) — shared
    const int j = lane >> 2, g = lane & 3;
    int jm1 = j - 1;
    int dh9 = ((jm1 * 11) >> 5) - 1;      // j in 1..9: (j-1)/3 - 1
    int dw9 = jm1 - (dh9 + 1) * 3 - 1;    // j in 1..9: (j-1)%3 - 1
    int df = (j >= 1 && j <= 9) ? -1 : 0;
    int dh = (j >= 1 && j <= 9) ? dh9 : ((j >= 10 && j <= 12) ? -1 : 0);
    int dw = (j >= 1 && j <= 9) ? dw9 :
             ((j >= 10 && j <= 12) ? (j - 11) : ((j == 13) ? -1 : 0));
    int nf = f + df, nh = hh + dh, nw = ww + dw;
    int valid = (nf >= 0) && ((unsigned)nh < 32u) && ((unsigned)nw < 32u)
                && (j >= 1) && (j <= 14);
    int p = valid ? (t + 1 + df * 1024 + dh * 32 + dw) : 0;   // j==0 -> BOS
    int score_on = valid || (j == 0);

    // ---- phase 1: scores, four heads interleaved
    const u16* qbase = QKV + baseQ + (size_t)(t + 1) * NQKV + hbase + g * 16;
    const u16* kbase = QKV + baseQ + (size_t)p * NQKV + 512 + hbase + g * 16;
    short8 qa[4], qb[4], ka[4], kb[4];
    #pragma unroll
    for (int hd = 0; hd < 4; ++hd) {
        qa[hd] = *(const short8*)(qbase + hd * 64);
        qb[hd] = *(const short8*)(qbase + hd * 64 + 8);
        ka[hd] = *(const short8*)(kbase + hd * 64);
        kb[hd] = *(const short8*)(kbase + hd * 64 + 8);
    }
    float s[4] = {};
    #pragma unroll
    for (int i = 0; i < 8; ++i)
        #pragma unroll
        for (int hd = 0; hd < 4; ++hd) {
            s[hd] = fmaf(b2f((u16)qa[hd][i]), b2f((u16)ka[hd][i]), s[hd]);
            s[hd] = fmaf(b2f((u16)qb[hd][i]), b2f((u16)kb[hd][i]), s[hd]);
        }
    #pragma unroll
    for (int hd = 0; hd < 4; ++hd) {
        s[hd] += __shfl_xor(s[hd], 1);
        s[hd] += __shfl_xor(s[hd], 2);    // 4 g-lanes of slot j hold dot_j
        s[hd] *= 0.125f;                  // SCALE
        s[hd] = score_on ? s[hd] : -3.0e38f;
    }
    float m[4] = {s[0], s[1], s[2], s[3]};
    #pragma unroll
    for (int off = 4; off <= 32; off <<= 1)
        #pragma unroll
        for (int hd = 0; hd < 4; ++hd)
            m[hd] = fmaxf(m[hd], __shfl_xor(m[hd], off));
    float pe[4], l[4];
    #pragma unroll
    for (int hd = 0; hd < 4; ++hd) {
        pe[hd] = __expf(s[hd] - m[hd]);   // masked lanes -> 0
        l[hd] = pe[hd];
    }
    #pragma unroll
    for (int off = 4; off <= 32; off <<= 1)
        #pragma unroll
        for (int hd = 0; hd < 4; ++hd)
            l[hd] += __shfl_xor(l[hd], off);
    float pen[4];
    #pragma unroll
    for (int hd = 0; hd < 4; ++hd)
        pen[hd] = pe[hd] * __frcp_rn(l[hd]);   // normalized, wave-wide
    u32 voff = (u32)p * 3072u;            // byte offset of V row p (shared)

    // ---- phase 2: PV, lane = dim, four heads
    float acc[4] = {};
    const char* vb[4];
    #pragma unroll
    for (int hd = 0; hd < 4; ++hd)
        vb[hd] = (const char*)(QKV + baseQ + 1024 + hbase + hd * 64 + lane);
    #pragma unroll
    for (int jj = 0; jj < 15; ++jj) {
        u32 o = (u32)__builtin_amdgcn_readlane((int)voff, jj * 4);
        #pragma unroll
        for (int hd = 0; hd < 4; ++hd) {
            float pj = __uint_as_float(
                         (u32)__builtin_amdgcn_readlane((int)__float_as_uint(pen[hd]), jj * 4));
            acc[hd] = fmaf(pj, b2f(*(const u16*)(vb[hd] + o)), acc[hd]);
        }
    }
    #pragma unroll
    for (int hd = 0; hd < 4; ++hd)
        O[baseO + (size_t)ti * DIM + hbase + hd * 64 + lane] = f2bf(acc[hd]);
}

// ---------------------------------------------------------------------------
// launch: cast -> gemm1 (QKV) -> attn -> gemm2 (out proj + bias)
// ws layout (bytes): xb 8M @0 | Wt 1.5M @8388608 | Wot 0.5M @9961472 |
//                    QKV 24M @10485760 | O aliases xb @0   (total ~34MB)
// ---------------------------------------------------------------------------
extern "C" void kernel_launch(void* const* d_in, const int* in_sizes, int n_in,
                              void* d_out, int out_size, void* d_ws, size_t ws_size,
                              hipStream_t stream) {
    const float* x   = (const float*)d_in[0];
    const float* Wq  = (const float*)d_in[1];
    const float* Wkv = (const float*)d_in[2];
    const float* Wo  = (const float*)d_in[3];
    const float* bo  = (const float*)d_in[4];
    float* out = (float*)d_out;
    char* ws = (char*)d_ws;

    u16* xb  = (u16*)(ws + 0);
    u16* Wt  = (u16*)(ws + 8388608);
    u16* Wot = (u16*)(ws + 9961472);
    u16* QKV = (u16*)(ws + 10485760);
    u16* O   = (u16*)(ws + 0);          // aliases xb (dead after gemm1)

    cast_all_kernel<<<dim3(4352), dim3(256), 0, stream>>>(
        (const float4*)x, Wq, Wkv, Wo, xb, Wt, Wot);
    gemm_nt<128, 128, 0><<<dim3(12, 64), dim3(256), 0, stream>>>(
        xb, Wt, (void*)QKV, nullptr, 512, 512, 1536);
    attn_kernel<<<dim3(4096), dim3(256), 0, stream>>>(QKV, O);
    gemm_nt<128, 64, 1><<<dim3(8, 64), dim3(256), 0, stream>>>(
        O, Wot, (void*)out, bo, 512, 512, 512);
}

// Round 14
// 132.653 us; speedup vs baseline: 1.1799x; 1.0124x over previous
//
#include <hip/hip_runtime.h>

// ---------------------------------------------------------------------------
// Sparse3DNA: x->QKV proj (bf16 MFMA GEMM), 3x3x3 causal window attention
// (+BOS), output proj. Shapes: b=2, T=4096 (4x32x32), DIM=512, 8 heads x 64.
// R14: attn v7 — v6 (4 heads/wave) with contiguous V phase: lane=(head,dim4),
// ONE dwordx2 load covers all 4 heads per slot (15 loads vs 60), pj via
// per-wave LDS table (1 ds_read_b32/slot), coalesced 8B store.
// GEMMs/cast = R9/R13 (best). Budget (R10): F~75us harness-fixed.
// ---------------------------------------------------------------------------

#define T_TOK   4096
#define DIM     512
#define NQKV    1536

typedef unsigned short u16;
typedef unsigned int   u32;
typedef unsigned long long u64;
typedef __attribute__((ext_vector_type(8))) short short8;   // 8 bf16 (4 VGPR)
typedef __attribute__((ext_vector_type(4))) float f32x4;

__device__ __forceinline__ u16 f2bf(float f) {           // RNE float->bf16
    u32 u = __float_as_uint(f);
    return (u16)((u + 0x7fffu + ((u >> 16) & 1u)) >> 16);
}
__device__ __forceinline__ float b2f(u16 u) {
    return __uint_as_float(((u32)u) << 16);
}

__device__ __forceinline__ void gload_lds16(const void* g, void* l) {
    // async global->LDS, 16B/lane; LDS dest = wave-uniform base + lane*16
    __builtin_amdgcn_global_load_lds(
        (const __attribute__((address_space(1))) void*)g,
        (__attribute__((address_space(3))) void*)l, 16, 0, 0);
}

// ---------------------------------------------------------------------------
// merged cast kernel.
//  blocks [0,4096): x fp32 -> bf16 (vectorized)
//  blocks [4096,4288): Wt[n][k] = [Wq|Wk|Wv](k,n), LDS-tiled 64x64 transpose
//  blocks [4288,4352): Wot[n][k] = Wo[k][n], same
// ---------------------------------------------------------------------------
__global__ void cast_all_kernel(const float4* __restrict__ x,
                                const float* __restrict__ Wq, const float* __restrict__ Wkv,
                                const float* __restrict__ Wo,
                                u16* __restrict__ xb, u16* __restrict__ Wt,
                                u16* __restrict__ Wot) {
    __shared__ float S[64 * 65];
    int blk = blockIdx.x;
    int tid = threadIdx.x;
    if (blk < 4096) {
        int i = blk * 256 + tid;                  // 1,048,576 float4s
        float4 v = x[i];
        u64 pack = (u64)f2bf(v.x) | ((u64)f2bf(v.y) << 16) |
                   ((u64)f2bf(v.z) << 32) | ((u64)f2bf(v.w) << 48);
        ((u64*)xb)[i] = pack;
        return;
    }
    int isWo = blk >= 4288;
    int tIdx = isWo ? (blk - 4288) : (blk - 4096);
    int tn = tIdx >> 3, tk = tIdx & 7;            // n-tile, k-tile
    #pragma unroll
    for (int p = 0; p < 16; ++p) {                // stage, coalesced over n
        int kl = p * 4 + (tid >> 6), nl = tid & 63;
        int gk = tk * 64 + kl, gn = tn * 64 + nl;
        float v;
        if (isWo)            v = Wo[gk * 512 + gn];
        else if (gn < 512)   v = Wq[gk * 512 + gn];
        else                 v = Wkv[gk * 1024 + (gn - 512)];
        S[kl * 65 + nl] = v;
    }
    __syncthreads();
    u16* dst = isWo ? Wot : Wt;
    #pragma unroll
    for (int p = 0; p < 16; ++p) {                // write, coalesced over k
        int nl = p * 4 + (tid >> 6), kl = tid & 63;
        dst[(size_t)(tn * 64 + nl) * 512 + tk * 64 + kl] = f2bf(S[kl * 65 + nl]);
    }
}

// ---------------------------------------------------------------------------
// NT GEMM, double-buffered (best of 6 variants): C = A * B^T, K=512, bf16.
// BMxBN / block, 4 waves (2x2), mfma 16x16x32, BK=32, XOR-swizzled LDS.
// K-loop: stage(ks+1 -> buf^1); s_waitcnt vmcnt(NLD); s_barrier; frags+MFMA;
// lgkmcnt(0); s_barrier.  MODE 0: bf16 store. MODE 1: fp32 store + bias.
// ---------------------------------------------------------------------------
template <int BM, int BN, int MODE>
__global__ __launch_bounds__(256)
void gemm_nt(const u16* __restrict__ A, const u16* __restrict__ B,
             void* __restrict__ Cv, const float* __restrict__ bias,
             int lda, int ldb, int ldc) {
    constexpr int K = 512, BK = 32, KSTEPS = K / BK;
    constexpr int ACH = BM * 4;                  // A 16B-chunks per K-step
    constexpr int NCH = (BM + BN) * 4;
    constexpr int NLD = NCH / 256;               // chunks per thread per stage
    constexpr int ABYTES = BM * 64;
    constexpr int HALF = (BM + BN) * 64;         // one buffer
    constexpr int MI = BM / 32, NJ = BN / 32;
    __shared__ __align__(16) char lds[2 * HALF];
    const int tid  = threadIdx.x;
    const int lane = tid & 63, wave = tid >> 6;
    const int quad = lane >> 4, mrow = lane & 15;
    const int wm = wave >> 1, wn = wave & 1;
    const int bm = blockIdx.y, bn = blockIdx.x;

    const char* gptr[NLD];
    char*       lptr[NLD];
    #pragma unroll
    for (int it = 0; it < NLD; ++it) {
        int c   = it * 256 + tid;                // chunk id, lane-consecutive
        int inB = (c >= ACH);
        int a   = inB ? c - ACH : c;
        int r   = a >> 2;                        // tile row
        int kc  = ((a & 3) - (r >> 1)) & 3;      // inverse swizzle
        int row = (inB ? bn * BN : bm * BM) + r;
        const u16* base = inB ? B : A;
        int ld = inB ? ldb : lda;
        gptr[it] = (const char*)(base + (size_t)row * ld + kc * 8);
        lptr[it] = (char*)lds + (it * 256 + wave * 64) * 16;   // wave-uniform
    }
    const char* aLds[MI];
    const char* bLds[NJ];
    #pragma unroll
    for (int i = 0; i < MI; ++i) {
        int ra = wm * (BM / 2) + i * 16 + mrow;
        aLds[i] = lds + (ra * 4 + ((quad + (ra >> 1)) & 3)) * 16;
    }
    #pragma unroll
    for (int j = 0; j < NJ; ++j) {
        int rb = wn * (BN / 2) + j * 16 + mrow;
        bLds[j] = lds + ABYTES + (rb * 4 + ((quad + (rb >> 1)) & 3)) * 16;
    }

    f32x4 acc[MI][NJ] = {};
    #pragma unroll
    for (int it = 0; it < NLD; ++it)             // prologue: stage 0 -> buf 0
        gload_lds16(gptr[it], lptr[it]);

    #pragma unroll
    for (int ks = 0; ks < KSTEPS; ++ks) {
        const int cur = ks & 1;
        if (ks + 1 < KSTEPS) {                   // prefetch next stage
            #pragma unroll
            for (int it = 0; it < NLD; ++it)
                gload_lds16(gptr[it] + 2 * (ks + 1) * BK, lptr[it] + (cur ^ 1) * HALF);
            asm volatile("s_waitcnt vmcnt(%0)" :: "i"(NLD) : "memory");
        } else {
            asm volatile("s_waitcnt vmcnt(0)" ::: "memory");
        }
        asm volatile("s_barrier" ::: "memory");  // stage ks visible to all

        short8 af[MI], bf[NJ];
        #pragma unroll
        for (int i = 0; i < MI; ++i) af[i] = *(const short8*)(aLds[i] + cur * HALF);
        #pragma unroll
        for (int j = 0; j < NJ; ++j) bf[j] = *(const short8*)(bLds[j] + cur * HALF);
        #pragma unroll
        for (int i = 0; i < MI; ++i)
            #pragma unroll
            for (int j = 0; j < NJ; ++j)
                acc[i][j] = __builtin_amdgcn_mfma_f32_16x16x32_bf16(af[i], bf[j], acc[i][j], 0, 0, 0);
        asm volatile("s_waitcnt lgkmcnt(0)" ::: "memory");
        asm volatile("s_barrier" ::: "memory");  // all waves done reading buf
    }

    // epilogue: D row = quad*4 + reg, col = lane&15 (m89-verified layout)
    #pragma unroll
    for (int i = 0; i < MI; ++i) {
        #pragma unroll
        for (int j = 0; j < NJ; ++j) {
            int colg = bn * BN + wn * (BN / 2) + j * 16 + mrow;
            #pragma unroll
            for (int r = 0; r < 4; ++r) {
                int rowg = bm * BM + wm * (BM / 2) + i * 16 + quad * 4 + r;
                if (MODE == 0) {
                    ((u16*)Cv)[(size_t)rowg * ldc + colg] = f2bf(acc[i][j][r]);
                } else {
                    ((float*)Cv)[(size_t)rowg * ldc + colg] = acc[i][j][r] + bias[colg];
                }
            }
        }
    }
}

// ---------------------------------------------------------------------------
// Attention v7: one wave per (b, head-QUAD, ti) — 16384 waves.
// Phase 1 (scores) = v6: slot decode shared; 4 heads' Q/K dot + batched
// softmax chains interleaved; pen[hd] = normalized weight, slot j at lane j*4.
// Phase 2 (PV) NEW: lane = (head = lane>>4, dimgroup = lane&15).
//   pj table in per-wave LDS: Pns[wave][hd*16+slot] (4 predicated ds_write);
//   per slot: readlane(voff) + ds_read_b32(pj, imm offset, 4-addr broadcast)
//   + ONE global_load_dwordx2 (512B/wave, all 4 heads) + 4 unpack + 4 fma.
//   Store: one coalesced 8B dwordx2 per lane.
// Loads 60->15, stores 4->1 per wave; identical per-element fma order.
// ---------------------------------------------------------------------------
__global__ __launch_bounds__(256)
void attn_kernel(const u16* __restrict__ QKV, u16* __restrict__ O) {
    __shared__ float Pns[4][64];
    const int wave = threadIdx.x >> 6;
    const int wid  = blockIdx.x * 4 + wave;      // 0..16383
    const int lane = threadIdx.x & 63;
    const int b  = wid >> 13;             // 2
    const int hp = (wid >> 12) & 1;       // head quad (0..1)
    const int ti = wid & 4095;            // 4096
    const size_t baseQ = (size_t)b * T_TOK * NQKV;
    const size_t baseO = (size_t)b * T_TOK * DIM;
    const int hbase = hp * 256;           // u16-col of head quad start

    if (ti == 0) {                        // output row 0 = bos_v (4 heads)
        #pragma unroll
        for (int hd = 0; hd < 4; ++hd)
            O[baseO + hbase + hd * 64 + lane] =
                QKV[baseQ + 1024 + hbase + hd * 64 + lane];
        return;
    }
    const int t = ti - 1;                 // grid position, 0..4094
    const int f = t >> 10, hh = (t >> 5) & 31, ww = t & 31;

    // ---- per-lane slot decode (wave-uniform t; j varies per lane) — shared
    const int j = lane >> 2, g = lane & 3;
    int jm1 = j - 1;
    int dh9 = ((jm1 * 11) >> 5) - 1;      // j in 1..9: (j-1)/3 - 1
    int dw9 = jm1 - (dh9 + 1) * 3 - 1;    // j in 1..9: (j-1)%3 - 1
    int df = (j >= 1 && j <= 9) ? -1 : 0;
    int dh = (j >= 1 && j <= 9) ? dh9 : ((j >= 10 && j <= 12) ? -1 : 0);
    int dw = (j >= 1 && j <= 9) ? dw9 :
             ((j >= 10 && j <= 12) ? (j - 11) : ((j == 13) ? -1 : 0));
    int nf = f + df, nh = hh + dh, nw = ww + dw;
    int valid = (nf >= 0) && ((unsigned)nh < 32u) && ((unsigned)nw < 32u)
                && (j >= 1) && (j <= 14);
    int p = valid ? (t + 1 + df * 1024 + dh * 32 + dw) : 0;   // j==0 -> BOS
    int score_on = valid || (j == 0);

    // ---- phase 1: scores, four heads interleaved
    const u16* qbase = QKV + baseQ + (size_t)(t + 1) * NQKV + hbase + g * 16;
    const u16* kbase = QKV + baseQ + (size_t)p * NQKV + 512 + hbase + g * 16;
    short8 qa[4], qb[4], ka[4], kb[4];
    #pragma unroll
    for (int hd = 0; hd < 4; ++hd) {
        qa[hd] = *(const short8*)(qbase + hd * 64);
        qb[hd] = *(const short8*)(qbase + hd * 64 + 8);
        ka[hd] = *(const short8*)(kbase + hd * 64);
        kb[hd] = *(const short8*)(kbase + hd * 64 + 8);
    }
    float s[4] = {};
    #pragma unroll
    for (int i = 0; i < 8; ++i)
        #pragma unroll
        for (int hd = 0; hd < 4; ++hd) {
            s[hd] = fmaf(b2f((u16)qa[hd][i]), b2f((u16)ka[hd][i]), s[hd]);
            s[hd] = fmaf(b2f((u16)qb[hd][i]), b2f((u16)kb[hd][i]), s[hd]);
        }
    #pragma unroll
    for (int hd = 0; hd < 4; ++hd) {
        s[hd] += __shfl_xor(s[hd], 1);
        s[hd] += __shfl_xor(s[hd], 2);    // 4 g-lanes of slot j hold dot_j
        s[hd] *= 0.125f;                  // SCALE
        s[hd] = score_on ? s[hd] : -3.0e38f;
    }
    float m[4] = {s[0], s[1], s[2], s[3]};
    #pragma unroll
    for (int off = 4; off <= 32; off <<= 1)
        #pragma unroll
        for (int hd = 0; hd < 4; ++hd)
            m[hd] = fmaxf(m[hd], __shfl_xor(m[hd], off));
    float pe[4], l[4];
    #pragma unroll
    for (int hd = 0; hd < 4; ++hd) {
        pe[hd] = __expf(s[hd] - m[hd]);   // masked lanes -> 0
        l[hd] = pe[hd];
    }
    #pragma unroll
    for (int off = 4; off <= 32; off <<= 1)
        #pragma unroll
        for (int hd = 0; hd < 4; ++hd)
            l[hd] += __shfl_xor(l[hd], off);
    u32 voff = (u32)p * 3072u;            // byte offset of V row p (shared)

    // ---- pj table: Pns[wave][hd*16 + slot], written by g==0 lanes
    if ((lane & 3) == 0) {
        int slot = lane >> 2;
        #pragma unroll
        for (int hd = 0; hd < 4; ++hd)
            Pns[wave][hd * 16 + slot] = pe[hd] * __frcp_rn(l[hd]);
    }
    asm volatile("s_waitcnt lgkmcnt(0)" ::: "memory");

    // ---- phase 2: PV; lane = (head = lane>>4, dims (lane&15)*4 .. +3)
    const float* ptab = &Pns[wave][(lane >> 4) * 16];
    const char* vrow = (const char*)(QKV + baseQ + 1024 + hbase) + lane * 8;
    float a0 = 0.f, a1 = 0.f, a2 = 0.f, a3 = 0.f;
    #pragma unroll
    for (int jj = 0; jj < 15; ++jj) {
        u32 o = (u32)__builtin_amdgcn_readlane((int)voff, jj * 4);
        float pj = ptab[jj];
        u64 v = *(const u64*)(vrow + o);          // 4 dims of lane's head
        u32 lo = (u32)v, hi = (u32)(v >> 32);
        a0 = fmaf(pj, __uint_as_float(lo << 16), a0);
        a1 = fmaf(pj, __uint_as_float(lo & 0xffff0000u), a1);
        a2 = fmaf(pj, __uint_as_float(hi << 16), a2);
        a3 = fmaf(pj, __uint_as_float(hi & 0xffff0000u), a3);
    }
    u64 pack = (u64)f2bf(a0) | ((u64)f2bf(a1) << 16) |
               ((u64)f2bf(a2) << 32) | ((u64)f2bf(a3) << 48);
    *(u64*)((char*)(O + baseO + (size_t)ti * DIM + hbase) + lane * 8) = pack;
}

// ---------------------------------------------------------------------------
// launch: cast -> gemm1 (QKV) -> attn -> gemm2 (out proj + bias)
// ws layout (bytes): xb 8M @0 | Wt 1.5M @8388608 | Wot 0.5M @9961472 |
//                    QKV 24M @10485760 | O aliases xb @0   (total ~34MB)
// ---------------------------------------------------------------------------
extern "C" void kernel_launch(void* const* d_in, const int* in_sizes, int n_in,
                              void* d_out, int out_size, void* d_ws, size_t ws_size,
                              hipStream_t stream) {
    const float* x   = (const float*)d_in[0];
    const float* Wq  = (const float*)d_in[1];
    const float* Wkv = (const float*)d_in[2];
    const float* Wo  = (const float*)d_in[3];
    const float* bo  = (const float*)d_in[4];
    float* out = (float*)d_out;
    char* ws = (char*)d_ws;

    u16* xb  = (u16*)(ws + 0);
    u16* Wt  = (u16*)(ws + 8388608);
    u16* Wot = (u16*)(ws + 9961472);
    u16* QKV = (u16*)(ws + 10485760);
    u16* O   = (u16*)(ws + 0);          // aliases xb (dead after gemm1)

    cast_all_kernel<<<dim3(4352), dim3(256), 0, stream>>>(
        (const float4*)x, Wq, Wkv, Wo, xb, Wt, Wot);
    gemm_nt<128, 128, 0><<<dim3(12, 64), dim3(256), 0, stream>>>(
        xb, Wt, (void*)QKV, nullptr, 512, 512, 1536);
    attn_kernel<<<dim3(4096), dim3(256), 0, stream>>>(QKV, O);
    gemm_nt<128, 64, 1><<<dim3(8, 64), dim3(256), 0, stream>>>(
        O, Wot, (void*)out, bo, 512, 512, 512);
}